// Round 1
// baseline (130.083 us; speedup 1.0000x reference)
//
#include <hip/hip_runtime.h>

#define NCLS 10

// Layout of d_out during accumulation:
//   out[0]        : loss (written by finalize)
//   out[1..10]    : per-class sum of (o-t)^2*m   -> overwritten in place with loss4each
//   out[11..20]   : per-class masked count (float, exact: count < 2^24)
__global__ __launch_bounds__(256) void loss_main(const float* __restrict__ outputs,
                                                 const int* __restrict__ targets,
                                                 const int* __restrict__ mask,
                                                 float* __restrict__ out,
                                                 int n) {
    float sum[NCLS];
    float cnt[NCLS];
#pragma unroll
    for (int c = 0; c < NCLS; ++c) { sum[c] = 0.0f; cnt[c] = 0.0f; }

    const int tid = blockIdx.x * blockDim.x + threadIdx.x;
    const int stride = gridDim.x * blockDim.x;
    const int nv = n >> 2;  // vec4 groups

    const float4* __restrict__ o4 = (const float4*)outputs;
    const int4*   __restrict__ t4 = (const int4*)targets;
    const int4*   __restrict__ m4 = (const int4*)mask;

    for (int i = tid; i < nv; i += stride) {
        float4 o = o4[i];
        int4   t = t4[i];
        int4   mk = m4[i];

        // element 0..3, branch-free class scatter into register bins
        {
            float m = (mk.x == 1) ? 1.0f : 0.0f;
            float d = o.x - (float)t.x; d = d * d * m;
#pragma unroll
            for (int c = 0; c < NCLS; ++c) {
                bool hit = (t.x == c);
                sum[c] += hit ? d : 0.0f;
                cnt[c] += hit ? m : 0.0f;
            }
        }
        {
            float m = (mk.y == 1) ? 1.0f : 0.0f;
            float d = o.y - (float)t.y; d = d * d * m;
#pragma unroll
            for (int c = 0; c < NCLS; ++c) {
                bool hit = (t.y == c);
                sum[c] += hit ? d : 0.0f;
                cnt[c] += hit ? m : 0.0f;
            }
        }
        {
            float m = (mk.z == 1) ? 1.0f : 0.0f;
            float d = o.z - (float)t.z; d = d * d * m;
#pragma unroll
            for (int c = 0; c < NCLS; ++c) {
                bool hit = (t.z == c);
                sum[c] += hit ? d : 0.0f;
                cnt[c] += hit ? m : 0.0f;
            }
        }
        {
            float m = (mk.w == 1) ? 1.0f : 0.0f;
            float d = o.w - (float)t.w; d = d * d * m;
#pragma unroll
            for (int c = 0; c < NCLS; ++c) {
                bool hit = (t.w == c);
                sum[c] += hit ? d : 0.0f;
                cnt[c] += hit ? m : 0.0f;
            }
        }
    }

    // scalar tail (n not divisible by 4 — not expected here, but safe)
    for (int i = (nv << 2) + tid; i < n; i += stride) {
        int t = targets[i];
        float m = (mask[i] == 1) ? 1.0f : 0.0f;
        float d = outputs[i] - (float)t; d = d * d * m;
#pragma unroll
        for (int c = 0; c < NCLS; ++c) {
            bool hit = (t == c);
            sum[c] += hit ? d : 0.0f;
            cnt[c] += hit ? m : 0.0f;
        }
    }

    // wave-64 butterfly reduction of all 20 accumulators
#pragma unroll
    for (int c = 0; c < NCLS; ++c) {
#pragma unroll
        for (int off = 32; off > 0; off >>= 1) {
            sum[c] += __shfl_xor(sum[c], off, 64);
            cnt[c] += __shfl_xor(cnt[c], off, 64);
        }
    }

    __shared__ float sp[4][2 * NCLS];  // blockDim=256 -> 4 waves
    const int lane = threadIdx.x & 63;
    const int wave = threadIdx.x >> 6;
    if (lane == 0) {
#pragma unroll
        for (int c = 0; c < NCLS; ++c) {
            sp[wave][c] = sum[c];
            sp[wave][NCLS + c] = cnt[c];
        }
    }
    __syncthreads();
    if (threadIdx.x < 2 * NCLS) {
        float v = sp[0][threadIdx.x] + sp[1][threadIdx.x] +
                  sp[2][threadIdx.x] + sp[3][threadIdx.x];
        atomicAdd(&out[1 + threadIdx.x], v);  // device-scope by default
    }
}

__global__ void loss_final(float* __restrict__ out) {
    const int c = threadIdx.x;
    float l4 = 0.0f;
    if (c < NCLS) {
        float s = out[1 + c];
        float n = out[11 + c];
        l4 = (n > 0.0f) ? (s / n) : 0.0f;   // n>0 implies n>=1, matches max(n,1)
        out[1 + c] = l4;                     // loss4each in place; out[11+c] stays class_n
    }
    float v = 0.1f * l4;                     // weight = 0.1 per class
#pragma unroll
    for (int off = 32; off > 0; off >>= 1) v += __shfl_xor(v, off, 64);
    if (c == 0) out[0] = v;
}

extern "C" void kernel_launch(void* const* d_in, const int* in_sizes, int n_in,
                              void* d_out, int out_size, void* d_ws, size_t ws_size,
                              hipStream_t stream) {
    const float* outputs = (const float*)d_in[0];
    const int*   targets = (const int*)d_in[1];
    const int*   mask    = (const int*)d_in[2];
    float* out = (float*)d_out;
    const int n = in_sizes[0];

    // d_out is re-poisoned to 0xAA before every timed launch — zero it ourselves.
    hipMemsetAsync(d_out, 0, (size_t)out_size * sizeof(float), stream);

    const int threads = 256;
    const int blocks = 512;  // 131072 threads, 16 vec4 iters each; 512 atomics/address
    loss_main<<<blocks, threads, 0, stream>>>(outputs, targets, mask, out, n);
    loss_final<<<1, 64, 0, stream>>>(out);
}